// Round 1
// baseline (837.840 us; speedup 1.0000x reference)
//
#include <hip/hip_runtime.h>
#include <hip/hip_bf16.h>
#include <stdint.h>

typedef __bf16 bf16_t;
typedef __attribute__((ext_vector_type(8))) __bf16 bf16x8;
typedef __attribute__((ext_vector_type(4))) __bf16 bf16x4;
typedef __attribute__((ext_vector_type(4))) float f32x4;

static constexpr int HDIM  = 2048;   // hidden dim
static constexpr int NBATCH = 4;
static constexpr int SEQ   = 2048;
static constexpr int MROWS = NBATCH * SEQ;  // 8192

// ---------------------------------------------------------------------------
// async global->LDS, 16B per lane. LDS dest = wave-uniform base + lane*16.
// ---------------------------------------------------------------------------
__device__ __forceinline__ void gload_lds16(const bf16_t* g, bf16_t* l) {
  __builtin_amdgcn_global_load_lds(
      (const __attribute__((address_space(1))) void*)g,
      (__attribute__((address_space(3))) void*)l, 16, 0, 0);
}

// ---------------------------------------------------------------------------
// NT GEMM: C[m,n] = sum_k A[m,k]*B[n,k].  A:(M,K) bf16 row-major, B:(N,K) bf16.
// 128x128 block tile, BK=64, 256 threads = 4 waves in 2x2, each wave 4x4
// mfma_f32_16x16x32_bf16 tiles.  M,N,K multiples of 128 (no bounds checks).
// MODE 0: C bf16.  MODE 1: C fp32.  MODE 2: atomicAdd(out, sum relu(c)*w2c[n]).
// ---------------------------------------------------------------------------
template<int MODE>
__global__ __launch_bounds__(256)
void gemm_nt(const bf16_t* __restrict__ Abase, const bf16_t* __restrict__ Bbase,
             void* __restrict__ Cbase, int M, int N, int K,
             long long sAz, long long sBz, long long sCz,
             const float* __restrict__ w2c, float* __restrict__ outp)
{
  __shared__ __align__(16) bf16_t sA[128 * 64];
  __shared__ __align__(16) bf16_t sB[128 * 64];

  const int tid  = threadIdx.x;
  const int wid  = tid >> 6;        // wave 0..3
  const int lane = tid & 63;
  const int bn = blockIdx.x, bm = blockIdx.y, z = blockIdx.z;

  const bf16_t* A = Abase + (long long)z * sAz + (long long)bm * 128 * K;
  const bf16_t* B = Bbase + (long long)z * sBz + (long long)bn * 128 * K;

  const int wr  = (wid >> 1) << 6;  // wave row offset (0 or 64)
  const int wc  = (wid & 1) << 6;   // wave col offset (0 or 64)
  const int m16 = lane & 15;
  const int q4  = lane >> 4;        // quad 0..3

  f32x4 acc[4][4];
#pragma unroll
  for (int i = 0; i < 4; i++)
#pragma unroll
    for (int j = 0; j < 4; j++)
#pragma unroll
      for (int r = 0; r < 4; r++) acc[i][j][r] = 0.0f;

  for (int k0 = 0; k0 < K; k0 += 64) {
    __syncthreads();  // previous iteration's LDS reads complete
    // --- stage A,B tiles: 16KB each = 1024 x16B chunks; 4 rounds of 256 ---
#pragma unroll
    for (int rnd = 0; rnd < 4; rnd++) {
      const int cid  = rnd * 256 + tid;     // chunk id
      const int row  = cid >> 3;            // 8 chunks (128B) per row of 64 bf16
      const int koct = cid & 7;
      const long long goff = (long long)row * K + k0 + koct * 8;
      bf16_t* la = sA + (rnd * 256 + wid * 64) * 8;  // wave-uniform LDS base
      bf16_t* lb = sB + (rnd * 256 + wid * 64) * 8;
      gload_lds16(A + goff, la);
      gload_lds16(B + goff, lb);
    }
    __syncthreads();  // compiler drains vmcnt before s_barrier

    // --- compute: 2 K-halves x 16 MFMA ---
#pragma unroll
    for (int kk = 0; kk < 64; kk += 32) {
      bf16x8 fa[4], fb[4];
#pragma unroll
      for (int i = 0; i < 4; i++)
        fa[i] = *(const bf16x8*)(sA + (wr + i * 16 + m16) * 64 + kk + q4 * 8);
#pragma unroll
      for (int j = 0; j < 4; j++)
        fb[j] = *(const bf16x8*)(sB + (wc + j * 16 + m16) * 64 + kk + q4 * 8);
#pragma unroll
      for (int i = 0; i < 4; i++)
#pragma unroll
        for (int j = 0; j < 4; j++)
          acc[i][j] = __builtin_amdgcn_mfma_f32_16x16x32_bf16(
              fa[i], fb[j], acc[i][j], 0, 0, 0);
    }
  }

  // C/D layout (m89/m91 verified): col = lane&15, row = (lane>>4)*4 + reg
  const int gr0 = bm * 128 + wr + q4 * 4;
  const int gc0 = bn * 128 + wc + m16;

  if (MODE == 0) {
    bf16_t* C = (bf16_t*)Cbase + (long long)z * sCz;
#pragma unroll
    for (int i = 0; i < 4; i++)
#pragma unroll
      for (int r = 0; r < 4; r++) {
        const long long ro = (long long)(gr0 + i * 16 + r) * N;
#pragma unroll
        for (int j = 0; j < 4; j++)
          C[ro + gc0 + j * 16] = (bf16_t)acc[i][j][r];
      }
  } else if (MODE == 1) {
    float* C = (float*)Cbase + (long long)z * sCz;
#pragma unroll
    for (int i = 0; i < 4; i++)
#pragma unroll
      for (int r = 0; r < 4; r++) {
        const long long ro = (long long)(gr0 + i * 16 + r) * N;
#pragma unroll
        for (int j = 0; j < 4; j++)
          C[ro + gc0 + j * 16] = acc[i][j][r];
      }
  } else {
    float w2[4];
#pragma unroll
    for (int j = 0; j < 4; j++) w2[j] = w2c[gc0 + j * 16];
    float s = 0.f;
#pragma unroll
    for (int i = 0; i < 4; i++)
#pragma unroll
      for (int j = 0; j < 4; j++)
#pragma unroll
        for (int r = 0; r < 4; r++) {
          const float v = acc[i][j][r];
          s += (v > 0.f) ? v * w2[j] : 0.f;
        }
#pragma unroll
    for (int off = 32; off > 0; off >>= 1) s += __shfl_down(s, off, 64);
    __shared__ float red[4];
    if (lane == 0) red[wid] = s;
    __syncthreads();
    if (tid == 0) atomicAdd(outp, red[0] + red[1] + red[2] + red[3]);
  }
}

// ---------------------------------------------------------------------------
// helpers
// ---------------------------------------------------------------------------
__global__ void cvt_bf16_kernel(const float* __restrict__ in,
                                bf16_t* __restrict__ out, long long n4) {
  const long long i = (long long)blockIdx.x * blockDim.x + threadIdx.x;
  if (i < n4) {
    const float4 v = ((const float4*)in)[i];
    bf16x4 o;
    o[0] = (bf16_t)v.x; o[1] = (bf16_t)v.y; o[2] = (bf16_t)v.z; o[3] = (bf16_t)v.w;
    ((bf16x4*)out)[i] = o;
  }
}

// out[h,m] = in[m,h], fp32 -> bf16.  grid(64,64), block(32,8)
__global__ void transpose_cvt_kernel(const float* __restrict__ in,
                                     bf16_t* __restrict__ out) {
  __shared__ float t[32][33];
  const int bx = blockIdx.x * 32, by = blockIdx.y * 32;
  const int x = threadIdx.x, y0 = threadIdx.y;
  for (int y = y0; y < 32; y += 8)
    t[y][x] = in[(long long)(by + y) * HDIM + bx + x];
  __syncthreads();
  for (int y = y0; y < 32; y += 8)
    out[(long long)(bx + y) * HDIM + by + x] = (bf16_t)t[x][y];
}

__global__ void zero_kernel(float* __restrict__ w2c, float* __restrict__ outp) {
  const int t = blockIdx.x * blockDim.x + threadIdx.x;
  if (t < HDIM) w2c[t] = 0.f;
  if (t == 0) outp[0] = 0.f;
}

// w2c[h] += sum over 128 rows of W2[d,h].  grid(8,16), block 256
__global__ void colsum_kernel(const float* __restrict__ W2,
                              float* __restrict__ w2c) {
  const int h  = blockIdx.x * 256 + threadIdx.x;
  const int d0 = blockIdx.y * 128;
  float s = 0.f;
#pragma unroll 4
  for (int d = 0; d < 128; d++) s += W2[(long long)(d0 + d) * HDIM + h];
  atomicAdd(&w2c[h], s);
}

// row softmax: S (fp32, row of 2048) -> P (bf16).  grid = MROWS, block 256
__global__ __launch_bounds__(256)
void softmax_kernel(const float* __restrict__ S, bf16_t* __restrict__ P) {
  const long long row = blockIdx.x;
  const float* s = S + row * HDIM;
  bf16_t* p = P + row * HDIM;
  const int t = threadIdx.x;
  const int wid = t >> 6, lane = t & 63;
  float v[8];
  float mx = -3.0e38f;
#pragma unroll
  for (int i = 0; i < 8; i++) { v[i] = s[t + i * 256]; mx = fmaxf(mx, v[i]); }
#pragma unroll
  for (int off = 32; off > 0; off >>= 1) mx = fmaxf(mx, __shfl_xor(mx, off, 64));
  __shared__ float sred[4];
  if (lane == 0) sred[wid] = mx;
  __syncthreads();
  mx = fmaxf(fmaxf(sred[0], sred[1]), fmaxf(sred[2], sred[3]));
  float sum = 0.f;
#pragma unroll
  for (int i = 0; i < 8; i++) { v[i] = __expf(v[i] - mx); sum += v[i]; }
#pragma unroll
  for (int off = 32; off > 0; off >>= 1) sum += __shfl_xor(sum, off, 64);
  __syncthreads();  // before reusing sred
  if (lane == 0) sred[wid] = sum;
  __syncthreads();
  sum = sred[0] + sred[1] + sred[2] + sred[3];
  const float inv = 1.0f / sum;
#pragma unroll
  for (int i = 0; i < 8; i++) p[t + i * 256] = (bf16_t)(v[i] * inv);
}

// ---------------------------------------------------------------------------
extern "C" void kernel_launch(void* const* d_in, const int* in_sizes, int n_in,
                              void* d_out, int out_size, void* d_ws, size_t ws_size,
                              hipStream_t stream)
{
  const float* x  = (const float*)d_in[0];
  const float* Wq = (const float*)d_in[1];
  const float* Wk = (const float*)d_in[2];
  const float* Wv = (const float*)d_in[3];
  const float* Wo = (const float*)d_in[4];
  const float* W1 = (const float*)d_in[5];
  const float* W2 = (const float*)d_in[6];
  float* out = (float*)d_out;

  const long long HH = (long long)HDIM * HDIM;   // 4,194,304
  const long long XE = (long long)MROWS * HDIM;  // 16,777,216

  // workspace layout (~185 MB):
  char* p = (char*)d_ws;
  bf16_t* xb   = (bf16_t*)p; p += XE * 2;   // 33.5 MB  (dead after vT gemm)
  bf16_t* Wqb  = (bf16_t*)p; p += HH * 2;   // dead after q gemm
  bf16_t* Wkb  = (bf16_t*)p; p += HH * 2;   // dead after k gemm
  bf16_t* Wvb  = (bf16_t*)p; p += HH * 2;   // dead after vT gemm
  bf16_t* W1b  = (bf16_t*)p; p += HH * 2;   // dead after Wow gemm
  bf16_t* WoTb = (bf16_t*)p; p += HH * 2;   // dead after Wow gemm
  // fp32 score (4*HH*4 = 67.1 MB) aliases [xb .. W1b] (75.5 MB), all dead
  // by the time the score gemm writes it.
  float* score = (float*)d_ws;
  bf16_t* Wowb = (bf16_t*)p; p += HH * 2;
  bf16_t* qb   = (bf16_t*)p; p += XE * 2;   // q, then softmax P
  bf16_t* kb   = (bf16_t*)p; p += XE * 2;   // k, then attn
  bf16_t* vTb  = (bf16_t*)p; p += XE * 2;   // vT (batch, d, j)
  float*  w2c  = (float*)p;  p += HDIM * 4;

  const dim3 b256(256);

  // 0. zero accumulators (d_out and d_ws are poisoned 0xAA before each run)
  zero_kernel<<<dim3(8), b256, 0, stream>>>(w2c, out);

  // 1. fp32 -> bf16 converts + Wo transpose + W2 column sums
  cvt_bf16_kernel<<<dim3((unsigned)(XE / 4 / 256)), b256, 0, stream>>>(x,  xb,  XE / 4);
  cvt_bf16_kernel<<<dim3((unsigned)(HH / 4 / 256)), b256, 0, stream>>>(Wq, Wqb, HH / 4);
  cvt_bf16_kernel<<<dim3((unsigned)(HH / 4 / 256)), b256, 0, stream>>>(Wk, Wkb, HH / 4);
  cvt_bf16_kernel<<<dim3((unsigned)(HH / 4 / 256)), b256, 0, stream>>>(Wv, Wvb, HH / 4);
  cvt_bf16_kernel<<<dim3((unsigned)(HH / 4 / 256)), b256, 0, stream>>>(W1, W1b, HH / 4);
  transpose_cvt_kernel<<<dim3(64, 64), dim3(32, 8), 0, stream>>>(Wo, WoTb);
  colsum_kernel<<<dim3(8, 16), b256, 0, stream>>>(W2, w2c);

  // 2. Wow[e,h] = sum_d W1[e,d]*Wo[d,h]  (NT vs WoT)
  gemm_nt<0><<<dim3(16, 16, 1), b256, 0, stream>>>(W1b, WoTb, Wowb,
      HDIM, HDIM, HDIM, 0, 0, 0, nullptr, nullptr);

  // 3. q = x@Wq^T, k = x@Wk^T   (M = 8192 folds the batch)
  gemm_nt<0><<<dim3(16, 64, 1), b256, 0, stream>>>(xb, Wqb, qb,
      MROWS, HDIM, HDIM, 0, 0, 0, nullptr, nullptr);
  gemm_nt<0><<<dim3(16, 64, 1), b256, 0, stream>>>(xb, Wkb, kb,
      MROWS, HDIM, HDIM, 0, 0, 0, nullptr, nullptr);

  // 4. vT[b,d,j] = sum_h Wv[d,h]*x[b,j,h]   (batched NT, A shared)
  gemm_nt<0><<<dim3(16, 16, 4), b256, 0, stream>>>(Wvb, xb, vTb,
      HDIM, HDIM, HDIM, 0, HH, HH, nullptr, nullptr);

  // 5. score[b,i,j] = sum_d q[b,i,d]*k[b,j,d]   (fp32 logits)
  gemm_nt<1><<<dim3(16, 16, 4), b256, 0, stream>>>(qb, kb, score,
      HDIM, HDIM, HDIM, HH, HH, HH, nullptr, nullptr);

  // 6. P = softmax(score) -> overwrite qb (q is dead)
  softmax_kernel<<<dim3(MROWS), b256, 0, stream>>>(score, qb);

  // 7. attn[b,i,d] = sum_j P[b,i,j]*vT[b,d,j] -> overwrite kb (k is dead)
  gemm_nt<0><<<dim3(16, 16, 4), b256, 0, stream>>>(qb, vTb, kb,
      HDIM, HDIM, HDIM, HH, HH, HH, nullptr, nullptr);

  // 8. out += sum relu(attn @ Wow^T) * w2c[col]
  gemm_nt<2><<<dim3(16, 64, 1), b256, 0, stream>>>(kb, Wowb, nullptr,
      MROWS, HDIM, HDIM, 0, 0, 0, w2c, out);
}

// Round 2
// 769.685 us; speedup vs baseline: 1.0885x; 1.0885x over previous
//
#include <hip/hip_runtime.h>
#include <hip/hip_bf16.h>
#include <stdint.h>

typedef __bf16 bf16_t;
typedef __attribute__((ext_vector_type(8))) __bf16 bf16x8;
typedef __attribute__((ext_vector_type(4))) __bf16 bf16x4;
typedef __attribute__((ext_vector_type(4))) float f32x4;

static constexpr int HDIM  = 2048;   // hidden dim
static constexpr int NBATCH = 4;
static constexpr int SEQ   = 2048;
static constexpr int MROWS = NBATCH * SEQ;  // 8192

// ---------------------------------------------------------------------------
// async global->LDS, 16B per lane. LDS dest = wave-uniform base + lane*16.
// ---------------------------------------------------------------------------
__device__ __forceinline__ void gload_lds16(const bf16_t* g, bf16_t* l) {
  __builtin_amdgcn_global_load_lds(
      (const __attribute__((address_space(1))) void*)g,
      (__attribute__((address_space(3))) void*)l, 16, 0, 0);
}

// ---------------------------------------------------------------------------
// NT GEMM: C[m,n] = sum_k A[m,k]*B[n,k].  A:(M,K) bf16 row-major, B:(N,K) bf16.
// 128x128 block tile, BK=64, 256 threads = 4 waves in 2x2, each wave 4x4
// mfma_f32_16x16x32_bf16 tiles.  M,N,K multiples of 128 (no bounds checks).
//
// LDS tiles are XOR-swizzled to kill bank conflicts: physical 16B-octet
// position p within row r holds logical K-octet (p ^ (r&7)).  The swizzle is
// applied on the GLOBAL address during staging (global_load_lds forces LDS
// writes to be lane-order-contiguous — m104/m108), and inverted on the
// ds_read side.  R0 measured 2.5e7 conflict cycles/dispatch (~35% of time)
// from the un-swizzled 128B row stride.
//
// MODE 0: C bf16.  MODE 1: C fp32.  MODE 2: atomicAdd(out, sum relu(c)*w2c[n]).
// ---------------------------------------------------------------------------
template<int MODE>
__global__ __launch_bounds__(256)
void gemm_nt(const bf16_t* __restrict__ Abase, const bf16_t* __restrict__ Bbase,
             void* __restrict__ Cbase, int M, int N, int K,
             long long sAz, long long sBz, long long sCz,
             const float* __restrict__ w2c, float* __restrict__ outp)
{
  __shared__ __align__(16) bf16_t sA[128 * 64];
  __shared__ __align__(16) bf16_t sB[128 * 64];

  const int tid  = threadIdx.x;
  const int wid  = tid >> 6;        // wave 0..3
  const int lane = tid & 63;
  const int bn = blockIdx.x, bm = blockIdx.y, z = blockIdx.z;

  const bf16_t* A = Abase + (long long)z * sAz + (long long)bm * 128 * K;
  const bf16_t* B = Bbase + (long long)z * sBz + (long long)bn * 128 * K;

  const int wr  = (wid >> 1) << 6;  // wave row offset (0 or 64)
  const int wc  = (wid & 1) << 6;   // wave col offset (0 or 64)
  const int m16 = lane & 15;
  const int q4  = lane >> 4;        // quad 0..3
  const int sx  = m16 & 7;          // per-lane read-side swizzle xor

  f32x4 acc[4][4];
#pragma unroll
  for (int i = 0; i < 4; i++)
#pragma unroll
    for (int j = 0; j < 4; j++)
#pragma unroll
      for (int r = 0; r < 4; r++) acc[i][j][r] = 0.0f;

  for (int k0 = 0; k0 < K; k0 += 64) {
    __syncthreads();  // previous iteration's LDS reads complete
    // --- stage A,B tiles: 16KB each = 1024 x16B chunks; 4 rounds of 256 ---
    // physical slot cid=(row,p) fetches logical K-octet (p ^ (row&7))
#pragma unroll
    for (int rnd = 0; rnd < 4; rnd++) {
      const int cid  = rnd * 256 + tid;     // chunk id == LDS slot
      const int row  = cid >> 3;            // 8 chunks (128B) per row of 64 bf16
      const int koct = (cid & 7) ^ (row & 7);
      const long long goff = (long long)row * K + k0 + koct * 8;
      bf16_t* la = sA + (rnd * 256 + wid * 64) * 8;  // wave-uniform LDS base
      bf16_t* lb = sB + (rnd * 256 + wid * 64) * 8;
      gload_lds16(A + goff, la);
      gload_lds16(B + goff, lb);
    }
    __syncthreads();  // compiler drains vmcnt before s_barrier

    // --- compute: 2 K-halves x 16 MFMA ---
#pragma unroll
    for (int kk = 0; kk < 64; kk += 32) {
      const int ob = (kk >> 3);             // logical octet base: 0 or 4
      bf16x8 fa[4], fb[4];
#pragma unroll
      for (int i = 0; i < 4; i++) {
        const int po = (ob + q4) ^ sx;      // physical octet after swizzle
        fa[i] = *(const bf16x8*)(sA + (wr + i * 16 + m16) * 64 + po * 8);
      }
#pragma unroll
      for (int j = 0; j < 4; j++) {
        const int po = (ob + q4) ^ sx;
        fb[j] = *(const bf16x8*)(sB + (wc + j * 16 + m16) * 64 + po * 8);
      }
#pragma unroll
      for (int i = 0; i < 4; i++)
#pragma unroll
        for (int j = 0; j < 4; j++)
          acc[i][j] = __builtin_amdgcn_mfma_f32_16x16x32_bf16(
              fa[i], fb[j], acc[i][j], 0, 0, 0);
    }
  }

  // C/D layout (m89/m91 verified): col = lane&15, row = (lane>>4)*4 + reg
  const int gr0 = bm * 128 + wr + q4 * 4;
  const int gc0 = bn * 128 + wc + m16;

  if (MODE == 0) {
    bf16_t* C = (bf16_t*)Cbase + (long long)z * sCz;
#pragma unroll
    for (int i = 0; i < 4; i++)
#pragma unroll
      for (int r = 0; r < 4; r++) {
        const long long ro = (long long)(gr0 + i * 16 + r) * N;
#pragma unroll
        for (int j = 0; j < 4; j++)
          C[ro + gc0 + j * 16] = (bf16_t)acc[i][j][r];
      }
  } else if (MODE == 1) {
    float* C = (float*)Cbase + (long long)z * sCz;
#pragma unroll
    for (int i = 0; i < 4; i++)
#pragma unroll
      for (int r = 0; r < 4; r++) {
        const long long ro = (long long)(gr0 + i * 16 + r) * N;
#pragma unroll
        for (int j = 0; j < 4; j++)
          C[ro + gc0 + j * 16] = acc[i][j][r];
      }
  } else {
    float w2[4];
#pragma unroll
    for (int j = 0; j < 4; j++) w2[j] = w2c[gc0 + j * 16];
    float s = 0.f;
#pragma unroll
    for (int i = 0; i < 4; i++)
#pragma unroll
      for (int j = 0; j < 4; j++)
#pragma unroll
        for (int r = 0; r < 4; r++) {
          const float v = acc[i][j][r];
          s += (v > 0.f) ? v * w2[j] : 0.f;
        }
#pragma unroll
    for (int off = 32; off > 0; off >>= 1) s += __shfl_down(s, off, 64);
    __shared__ float red[4];
    if (lane == 0) red[wid] = s;
    __syncthreads();
    if (tid == 0) atomicAdd(outp, red[0] + red[1] + red[2] + red[3]);
  }
}

// ---------------------------------------------------------------------------
// helpers
// ---------------------------------------------------------------------------
__global__ void cvt_bf16_kernel(const float* __restrict__ in,
                                bf16_t* __restrict__ out, long long n4) {
  const long long i = (long long)blockIdx.x * blockDim.x + threadIdx.x;
  if (i < n4) {
    const float4 v = ((const float4*)in)[i];
    bf16x4 o;
    o[0] = (bf16_t)v.x; o[1] = (bf16_t)v.y; o[2] = (bf16_t)v.z; o[3] = (bf16_t)v.w;
    ((bf16x4*)out)[i] = o;
  }
}

// out[h,m] = in[m,h], fp32 -> bf16.  grid(64,64), block(32,8)
__global__ void transpose_cvt_kernel(const float* __restrict__ in,
                                     bf16_t* __restrict__ out) {
  __shared__ float t[32][33];
  const int bx = blockIdx.x * 32, by = blockIdx.y * 32;
  const int x = threadIdx.x, y0 = threadIdx.y;
  for (int y = y0; y < 32; y += 8)
    t[y][x] = in[(long long)(by + y) * HDIM + bx + x];
  __syncthreads();
  for (int y = y0; y < 32; y += 8)
    out[(long long)(bx + y) * HDIM + by + x] = (bf16_t)t[x][y];
}

__global__ void zero_kernel(float* __restrict__ w2c, float* __restrict__ outp) {
  const int t = blockIdx.x * blockDim.x + threadIdx.x;
  if (t < HDIM) w2c[t] = 0.f;
  if (t == 0) outp[0] = 0.f;
}

// w2c[h] += sum over 128 rows of W2[d,h].  grid(8,16), block 256
__global__ void colsum_kernel(const float* __restrict__ W2,
                              float* __restrict__ w2c) {
  const int h  = blockIdx.x * 256 + threadIdx.x;
  const int d0 = blockIdx.y * 128;
  float s = 0.f;
#pragma unroll 4
  for (int d = 0; d < 128; d++) s += W2[(long long)(d0 + d) * HDIM + h];
  atomicAdd(&w2c[h], s);
}

// row softmax: S (fp32, row of 2048) -> P (bf16).  grid = MROWS, block 256
__global__ __launch_bounds__(256)
void softmax_kernel(const float* __restrict__ S, bf16_t* __restrict__ P) {
  const long long row = blockIdx.x;
  const float* s = S + row * HDIM;
  bf16_t* p = P + row * HDIM;
  const int t = threadIdx.x;
  const int wid = t >> 6, lane = t & 63;
  float v[8];
  float mx = -3.0e38f;
#pragma unroll
  for (int i = 0; i < 8; i++) { v[i] = s[t + i * 256]; mx = fmaxf(mx, v[i]); }
#pragma unroll
  for (int off = 32; off > 0; off >>= 1) mx = fmaxf(mx, __shfl_xor(mx, off, 64));
  __shared__ float sred[4];
  if (lane == 0) sred[wid] = mx;
  __syncthreads();
  mx = fmaxf(fmaxf(sred[0], sred[1]), fmaxf(sred[2], sred[3]));
  float sum = 0.f;
#pragma unroll
  for (int i = 0; i < 8; i++) { v[i] = __expf(v[i] - mx); sum += v[i]; }
#pragma unroll
  for (int off = 32; off > 0; off >>= 1) sum += __shfl_xor(sum, off, 64);
  __syncthreads();  // before reusing sred
  if (lane == 0) sred[wid] = sum;
  __syncthreads();
  sum = sred[0] + sred[1] + sred[2] + sred[3];
  const float inv = 1.0f / sum;
#pragma unroll
  for (int i = 0; i < 8; i++) p[t + i * 256] = (bf16_t)(v[i] * inv);
}

// ---------------------------------------------------------------------------
extern "C" void kernel_launch(void* const* d_in, const int* in_sizes, int n_in,
                              void* d_out, int out_size, void* d_ws, size_t ws_size,
                              hipStream_t stream)
{
  const float* x  = (const float*)d_in[0];
  const float* Wq = (const float*)d_in[1];
  const float* Wk = (const float*)d_in[2];
  const float* Wv = (const float*)d_in[3];
  const float* Wo = (const float*)d_in[4];
  const float* W1 = (const float*)d_in[5];
  const float* W2 = (const float*)d_in[6];
  float* out = (float*)d_out;

  const long long HH = (long long)HDIM * HDIM;   // 4,194,304
  const long long XE = (long long)MROWS * HDIM;  // 16,777,216

  // workspace layout (~185 MB):
  char* p = (char*)d_ws;
  bf16_t* xb   = (bf16_t*)p; p += XE * 2;   // 33.5 MB  (dead after vT gemm)
  bf16_t* Wqb  = (bf16_t*)p; p += HH * 2;   // dead after q gemm
  bf16_t* Wkb  = (bf16_t*)p; p += HH * 2;   // dead after k gemm
  bf16_t* Wvb  = (bf16_t*)p; p += HH * 2;   // dead after vT gemm
  bf16_t* W1b  = (bf16_t*)p; p += HH * 2;   // dead after Wow gemm
  bf16_t* WoTb = (bf16_t*)p; p += HH * 2;   // dead after Wow gemm
  // fp32 score (4*HH*4 = 67.1 MB) aliases [xb .. W1b] (75.5 MB), all dead
  // by the time the score gemm writes it.
  float* score = (float*)d_ws;
  bf16_t* Wowb = (bf16_t*)p; p += HH * 2;
  bf16_t* qb   = (bf16_t*)p; p += XE * 2;   // q, then softmax P
  bf16_t* kb   = (bf16_t*)p; p += XE * 2;   // k, then attn
  bf16_t* vTb  = (bf16_t*)p; p += XE * 2;   // vT (batch, d, j)
  float*  w2c  = (float*)p;  p += HDIM * 4;

  const dim3 b256(256);

  // 0. zero accumulators (d_out and d_ws are poisoned 0xAA before each run)
  zero_kernel<<<dim3(8), b256, 0, stream>>>(w2c, out);

  // 1. fp32 -> bf16 converts + Wo transpose + W2 column sums
  cvt_bf16_kernel<<<dim3((unsigned)(XE / 4 / 256)), b256, 0, stream>>>(x,  xb,  XE / 4);
  cvt_bf16_kernel<<<dim3((unsigned)(HH / 4 / 256)), b256, 0, stream>>>(Wq, Wqb, HH / 4);
  cvt_bf16_kernel<<<dim3((unsigned)(HH / 4 / 256)), b256, 0, stream>>>(Wk, Wkb, HH / 4);
  cvt_bf16_kernel<<<dim3((unsigned)(HH / 4 / 256)), b256, 0, stream>>>(Wv, Wvb, HH / 4);
  cvt_bf16_kernel<<<dim3((unsigned)(HH / 4 / 256)), b256, 0, stream>>>(W1, W1b, HH / 4);
  transpose_cvt_kernel<<<dim3(64, 64), dim3(32, 8), 0, stream>>>(Wo, WoTb);
  colsum_kernel<<<dim3(8, 16), b256, 0, stream>>>(W2, w2c);

  // 2. Wow[e,h] = sum_d W1[e,d]*Wo[d,h]  (NT vs WoT)
  gemm_nt<0><<<dim3(16, 16, 1), b256, 0, stream>>>(W1b, WoTb, Wowb,
      HDIM, HDIM, HDIM, 0, 0, 0, nullptr, nullptr);

  // 3. q = x@Wq^T, k = x@Wk^T   (M = 8192 folds the batch)
  gemm_nt<0><<<dim3(16, 64, 1), b256, 0, stream>>>(xb, Wqb, qb,
      MROWS, HDIM, HDIM, 0, 0, 0, nullptr, nullptr);
  gemm_nt<0><<<dim3(16, 64, 1), b256, 0, stream>>>(xb, Wkb, kb,
      MROWS, HDIM, HDIM, 0, 0, 0, nullptr, nullptr);

  // 4. vT[b,d,j] = sum_h Wv[d,h]*x[b,j,h]   (batched NT, A shared)
  gemm_nt<0><<<dim3(16, 16, 4), b256, 0, stream>>>(Wvb, xb, vTb,
      HDIM, HDIM, HDIM, 0, HH, HH, nullptr, nullptr);

  // 5. score[b,i,j] = sum_d q[b,i,d]*k[b,j,d]   (fp32 logits)
  gemm_nt<1><<<dim3(16, 16, 4), b256, 0, stream>>>(qb, kb, score,
      HDIM, HDIM, HDIM, HH, HH, HH, nullptr, nullptr);

  // 6. P = softmax(score) -> overwrite qb (q is dead)
  softmax_kernel<<<dim3(MROWS), b256, 0, stream>>>(score, qb);

  // 7. attn[b,i,d] = sum_j P[b,i,j]*vT[b,d,j] -> overwrite kb (k is dead)
  gemm_nt<0><<<dim3(16, 16, 4), b256, 0, stream>>>(qb, vTb, kb,
      HDIM, HDIM, HDIM, HH, HH, HH, nullptr, nullptr);

  // 8. out += sum relu(attn @ Wow^T) * w2c[col]
  gemm_nt<2><<<dim3(16, 64, 1), b256, 0, stream>>>(kb, Wowb, nullptr,
      MROWS, HDIM, HDIM, 0, 0, 0, w2c, out);
}

// Round 3
// 717.179 us; speedup vs baseline: 1.1682x; 1.0732x over previous
//
#include <hip/hip_runtime.h>
#include <hip/hip_bf16.h>
#include <stdint.h>

typedef __bf16 bf16_t;
typedef __attribute__((ext_vector_type(8))) __bf16 bf16x8;
typedef __attribute__((ext_vector_type(4))) __bf16 bf16x4;
typedef __attribute__((ext_vector_type(4))) float f32x4;

static constexpr int HDIM  = 2048;   // hidden dim
static constexpr int NBATCH = 4;
static constexpr int SEQ   = 2048;
static constexpr int MROWS = NBATCH * SEQ;  // 8192

// ---------------------------------------------------------------------------
// async global->LDS, 16B per lane. LDS dest = wave-uniform base + lane*16.
// ---------------------------------------------------------------------------
__device__ __forceinline__ void gload_lds16(const bf16_t* g, bf16_t* l) {
  __builtin_amdgcn_global_load_lds(
      (const __attribute__((address_space(1))) void*)g,
      (__attribute__((address_space(3))) void*)l, 16, 0, 0);
}

// ---------------------------------------------------------------------------
// NT GEMM: C[m,n] = sum_k A[m,k]*B[n,k].  A:(M,K) bf16 row-major, B:(N,K) bf16.
// 128x128 block tile, BK=64, 256 threads = 4 waves in 2x2, each wave 4x4
// mfma_f32_16x16x32_bf16 tiles.  M,N,K multiples of 128 (no bounds checks).
//
// LDS tiles XOR-swizzled (R1: killed 2.5e7 conflict cycles/dispatch -> 0).
// Swizzle applied on the GLOBAL address during staging (global_load_lds
// forces lane-order-contiguous LDS writes — m104/m108), inverted on ds_read.
//
// MODE 0: C bf16.  MODE 1: C fp32.  MODE 2: atomicAdd(out, sum relu(c)*w2c[n]).
// ---------------------------------------------------------------------------
template<int MODE>
__global__ __launch_bounds__(256)
void gemm_nt(const bf16_t* __restrict__ Abase, const bf16_t* __restrict__ Bbase,
             void* __restrict__ Cbase, int M, int N, int K,
             long long sAz, long long sBz, long long sCz,
             const float* __restrict__ w2c, float* __restrict__ outp)
{
  __shared__ __align__(16) bf16_t sA[128 * 64];
  __shared__ __align__(16) bf16_t sB[128 * 64];

  const int tid  = threadIdx.x;
  const int wid  = tid >> 6;        // wave 0..3
  const int lane = tid & 63;
  const int bn = blockIdx.x, bm = blockIdx.y, z = blockIdx.z;

  const bf16_t* A = Abase + (long long)z * sAz + (long long)bm * 128 * K;
  const bf16_t* B = Bbase + (long long)z * sBz + (long long)bn * 128 * K;

  const int wr  = (wid >> 1) << 6;  // wave row offset (0 or 64)
  const int wc  = (wid & 1) << 6;   // wave col offset (0 or 64)
  const int m16 = lane & 15;
  const int q4  = lane >> 4;        // quad 0..3
  const int sx  = m16 & 7;          // per-lane read-side swizzle xor

  f32x4 acc[4][4];
#pragma unroll
  for (int i = 0; i < 4; i++)
#pragma unroll
    for (int j = 0; j < 4; j++)
#pragma unroll
      for (int r = 0; r < 4; r++) acc[i][j][r] = 0.0f;

  for (int k0 = 0; k0 < K; k0 += 64) {
    __syncthreads();  // previous iteration's LDS reads complete
    // --- stage A,B tiles: 16KB each = 1024 x16B chunks; 4 rounds of 256 ---
    // physical slot cid=(row,p) fetches logical K-octet (p ^ (row&7))
#pragma unroll
    for (int rnd = 0; rnd < 4; rnd++) {
      const int cid  = rnd * 256 + tid;     // chunk id == LDS slot
      const int row  = cid >> 3;            // 8 chunks (128B) per row of 64 bf16
      const int koct = (cid & 7) ^ (row & 7);
      const long long goff = (long long)row * K + k0 + koct * 8;
      bf16_t* la = sA + (rnd * 256 + wid * 64) * 8;  // wave-uniform LDS base
      bf16_t* lb = sB + (rnd * 256 + wid * 64) * 8;
      gload_lds16(A + goff, la);
      gload_lds16(B + goff, lb);
    }
    __syncthreads();  // compiler drains vmcnt before s_barrier

    // --- compute: 2 K-halves x 16 MFMA ---
#pragma unroll
    for (int kk = 0; kk < 64; kk += 32) {
      const int ob = (kk >> 3);             // logical octet base: 0 or 4
      bf16x8 fa[4], fb[4];
#pragma unroll
      for (int i = 0; i < 4; i++) {
        const int po = (ob + q4) ^ sx;      // physical octet after swizzle
        fa[i] = *(const bf16x8*)(sA + (wr + i * 16 + m16) * 64 + po * 8);
      }
#pragma unroll
      for (int j = 0; j < 4; j++) {
        const int po = (ob + q4) ^ sx;
        fb[j] = *(const bf16x8*)(sB + (wc + j * 16 + m16) * 64 + po * 8);
      }
#pragma unroll
      for (int i = 0; i < 4; i++)
#pragma unroll
        for (int j = 0; j < 4; j++)
          acc[i][j] = __builtin_amdgcn_mfma_f32_16x16x32_bf16(
              fa[i], fb[j], acc[i][j], 0, 0, 0);
    }
  }

  // C/D layout (m89/m91 verified): col = lane&15, row = (lane>>4)*4 + reg
  const int gr0 = bm * 128 + wr + q4 * 4;
  const int gc0 = bn * 128 + wc + m16;

  if (MODE == 0) {
    bf16_t* C = (bf16_t*)Cbase + (long long)z * sCz;
#pragma unroll
    for (int i = 0; i < 4; i++)
#pragma unroll
      for (int r = 0; r < 4; r++) {
        const long long ro = (long long)(gr0 + i * 16 + r) * N;
#pragma unroll
        for (int j = 0; j < 4; j++)
          C[ro + gc0 + j * 16] = (bf16_t)acc[i][j][r];
      }
  } else if (MODE == 1) {
    float* C = (float*)Cbase + (long long)z * sCz;
#pragma unroll
    for (int i = 0; i < 4; i++)
#pragma unroll
      for (int r = 0; r < 4; r++) {
        const long long ro = (long long)(gr0 + i * 16 + r) * N;
#pragma unroll
        for (int j = 0; j < 4; j++)
          C[ro + gc0 + j * 16] = acc[i][j][r];
      }
  } else {
    float w2[4];
#pragma unroll
    for (int j = 0; j < 4; j++) w2[j] = w2c[gc0 + j * 16];
    float s = 0.f;
#pragma unroll
    for (int i = 0; i < 4; i++)
#pragma unroll
      for (int j = 0; j < 4; j++)
#pragma unroll
        for (int r = 0; r < 4; r++) {
          const float v = acc[i][j][r];
          s += (v > 0.f) ? v * w2[j] : 0.f;
        }
#pragma unroll
    for (int off = 32; off > 0; off >>= 1) s += __shfl_down(s, off, 64);
    __shared__ float red[4];
    if (lane == 0) red[wid] = s;
    __syncthreads();
    if (tid == 0) atomicAdd(outp, red[0] + red[1] + red[2] + red[3]);
  }
}

// ---------------------------------------------------------------------------
// helpers
// ---------------------------------------------------------------------------
__global__ void cvt_bf16_kernel(const float* __restrict__ in,
                                bf16_t* __restrict__ out, long long n4) {
  const long long i = (long long)blockIdx.x * blockDim.x + threadIdx.x;
  if (i < n4) {
    const float4 v = ((const float4*)in)[i];
    bf16x4 o;
    o[0] = (bf16_t)v.x; o[1] = (bf16_t)v.y; o[2] = (bf16_t)v.z; o[3] = (bf16_t)v.w;
    ((bf16x4*)out)[i] = o;
  }
}

// out[h,m] = in[m,h], fp32 -> bf16.  grid(64,64), block(32,8)
__global__ void transpose_cvt_kernel(const float* __restrict__ in,
                                     bf16_t* __restrict__ out) {
  __shared__ float t[32][33];
  const int bx = blockIdx.x * 32, by = blockIdx.y * 32;
  const int x = threadIdx.x, y0 = threadIdx.y;
  for (int y = y0; y < 32; y += 8)
    t[y][x] = in[(long long)(by + y) * HDIM + bx + x];
  __syncthreads();
  for (int y = y0; y < 32; y += 8)
    out[(long long)(bx + y) * HDIM + by + x] = (bf16_t)t[x][y];
}

__global__ void zero_kernel(float* __restrict__ w2c, float* __restrict__ outp) {
  const int t = blockIdx.x * blockDim.x + threadIdx.x;
  if (t < HDIM) w2c[t] = 0.f;
  if (t == 0) outp[0] = 0.f;
}

// w2c[h] += sum over 128 rows of W2[d,h].  grid(8,16), block 256
__global__ void colsum_kernel(const float* __restrict__ W2,
                              float* __restrict__ w2c) {
  const int h  = blockIdx.x * 256 + threadIdx.x;
  const int d0 = blockIdx.y * 128;
  float s = 0.f;
#pragma unroll 4
  for (int d = 0; d < 128; d++) s += W2[(long long)(d0 + d) * HDIM + h];
  atomicAdd(&w2c[h], s);
}

// in-place row softmax on bf16 logits: row of 2048, grid=MROWS, block 256.
// Each thread owns 8 contiguous bf16 (one 16B vector); all reads complete
// (values in registers) before any write, so in-place is safe.
__global__ __launch_bounds__(256)
void softmax_bf16_kernel(bf16_t* __restrict__ S) {
  const long long row = blockIdx.x;
  bf16_t* s = S + row * HDIM;
  const int t = threadIdx.x;
  const int wid = t >> 6, lane = t & 63;
  const bf16x8 raw = ((const bf16x8*)s)[t];
  float v[8];
  float mx = -3.0e38f;
#pragma unroll
  for (int i = 0; i < 8; i++) { v[i] = (float)raw[i]; mx = fmaxf(mx, v[i]); }
#pragma unroll
  for (int off = 32; off > 0; off >>= 1) mx = fmaxf(mx, __shfl_xor(mx, off, 64));
  __shared__ float sred[4];
  if (lane == 0) sred[wid] = mx;
  __syncthreads();
  mx = fmaxf(fmaxf(sred[0], sred[1]), fmaxf(sred[2], sred[3]));
  float sum = 0.f;
#pragma unroll
  for (int i = 0; i < 8; i++) { v[i] = __expf(v[i] - mx); sum += v[i]; }
#pragma unroll
  for (int off = 32; off > 0; off >>= 1) sum += __shfl_xor(sum, off, 64);
  __syncthreads();  // before reusing sred
  if (lane == 0) sred[wid] = sum;
  __syncthreads();
  sum = sred[0] + sred[1] + sred[2] + sred[3];
  const float inv = 1.0f / sum;
  bf16x8 o;
#pragma unroll
  for (int i = 0; i < 8; i++) o[i] = (bf16_t)(v[i] * inv);
  ((bf16x8*)s)[t] = o;
}

// ---------------------------------------------------------------------------
extern "C" void kernel_launch(void* const* d_in, const int* in_sizes, int n_in,
                              void* d_out, int out_size, void* d_ws, size_t ws_size,
                              hipStream_t stream)
{
  const float* x  = (const float*)d_in[0];
  const float* Wq = (const float*)d_in[1];
  const float* Wk = (const float*)d_in[2];
  const float* Wv = (const float*)d_in[3];
  const float* Wo = (const float*)d_in[4];
  const float* W1 = (const float*)d_in[5];
  const float* W2 = (const float*)d_in[6];
  float* out = (float*)d_out;

  const long long HH = (long long)HDIM * HDIM;   // 4,194,304
  const long long XE = (long long)MROWS * HDIM;  // 16,777,216

  // workspace (~185 MB).  Algebra:
  //   score = x (Wq^T Wk) x^T            (saves the q,k GEMMs: -51.5 GF)
  //   post-attn = attn (W1 Wo)^T          (Wow fold, from R0)
  //   out = sum relu(.) . colsum(W2)      (W2 fold, from R0)
  char* p = (char*)d_ws;
  bf16_t* xb  = (bf16_t*)p; p += XE * 2;  // x bf16 (alive through vT gemm)
  bf16_t* S1  = (bf16_t*)p; p += HH * 2;  // WqT, then Wow
  bf16_t* S2  = (bf16_t*)p; p += HH * 2;  // WkT
  bf16_t* S3  = (bf16_t*)p; p += HH * 2;  // Wv bf16
  bf16_t* S4  = (bf16_t*)p; p += HH * 2;  // W1 bf16
  bf16_t* S5  = (bf16_t*)p; p += HH * 2;  // WoT
  bf16_t* S6  = (bf16_t*)p; p += HH * 2;  // WqkT = (Wq^T Wk)^T
  bf16_t* tb  = (bf16_t*)p; p += XE * 2;  // t = x.Wqk, then attn
  bf16_t* sc  = (bf16_t*)p; p += XE * 2;  // score -> P (in-place softmax)
  bf16_t* vTb = (bf16_t*)p; p += XE * 2;  // vT (batch, d, j)
  float*  w2c = (float*)p;  p += HDIM * 4;

  const dim3 b256(256);

  // 0. zero accumulators (d_out / d_ws re-poisoned 0xAA before every launch)
  zero_kernel<<<dim3(8), b256, 0, stream>>>(w2c, out);

  // 1. converts: x, Wv, W1 plain; Wq, Wk, Wo transposed; W2 column sums
  cvt_bf16_kernel<<<dim3((unsigned)(XE / 4 / 256)), b256, 0, stream>>>(x,  xb, XE / 4);
  transpose_cvt_kernel<<<dim3(64, 64), dim3(32, 8), 0, stream>>>(Wq, S1);
  transpose_cvt_kernel<<<dim3(64, 64), dim3(32, 8), 0, stream>>>(Wk, S2);
  transpose_cvt_kernel<<<dim3(64, 64), dim3(32, 8), 0, stream>>>(Wo, S5);
  cvt_bf16_kernel<<<dim3((unsigned)(HH / 4 / 256)), b256, 0, stream>>>(Wv, S3, HH / 4);
  cvt_bf16_kernel<<<dim3((unsigned)(HH / 4 / 256)), b256, 0, stream>>>(W1, S4, HH / 4);
  colsum_kernel<<<dim3(8, 16), b256, 0, stream>>>(W2, w2c);

  // 2a. WqkT[n,k] = sum_d Wk[d,n]*Wq[d,k]   ( = (Wq^T Wk)^T )
  gemm_nt<0><<<dim3(16, 16, 1), b256, 0, stream>>>(S2, S1, S6,
      HDIM, HDIM, HDIM, 0, 0, 0, nullptr, nullptr);
  // 2b. Wow[e,h] = sum_d W1[e,d]*Wo[d,h]   (S1 dead -> reuse for Wow)
  gemm_nt<0><<<dim3(16, 16, 1), b256, 0, stream>>>(S4, S5, S1,
      HDIM, HDIM, HDIM, 0, 0, 0, nullptr, nullptr);

  // 3. t = x @ Wqk   (t[m,n] = sum_k x[m,k]*WqkT[n,k])
  gemm_nt<0><<<dim3(16, 64, 1), b256, 0, stream>>>(xb, S6, tb,
      MROWS, HDIM, HDIM, 0, 0, 0, nullptr, nullptr);

  // 4. score[b,i,j] = sum_e t[b,i,e]*x[b,j,e]  (bf16 logits)
  gemm_nt<0><<<dim3(16, 16, 4), b256, 0, stream>>>(tb, xb, sc,
      HDIM, HDIM, HDIM, HH, HH, HH, nullptr, nullptr);

  // 5. vT[b,d,j] = sum_h Wv[d,h]*x[b,j,h]
  gemm_nt<0><<<dim3(16, 16, 4), b256, 0, stream>>>(S3, xb, vTb,
      HDIM, HDIM, HDIM, 0, HH, HH, nullptr, nullptr);

  // 6. P = softmax(score), in place
  softmax_bf16_kernel<<<dim3(MROWS), b256, 0, stream>>>(sc);

  // 7. attn[b,i,d] = sum_j P[b,i,j]*vT[b,d,j]  (t dead -> reuse tb)
  gemm_nt<0><<<dim3(16, 16, 4), b256, 0, stream>>>(sc, vTb, tb,
      HDIM, HDIM, HDIM, HH, HH, HH, nullptr, nullptr);

  // 8. out += sum relu(attn @ Wow^T) * w2c[col]
  gemm_nt<2><<<dim3(16, 64, 1), b256, 0, stream>>>(tb, S1, nullptr,
      MROWS, HDIM, HDIM, 0, 0, 0, w2c, out);
}

// Round 6
// 669.380 us; speedup vs baseline: 1.2517x; 1.0714x over previous
//
#include <hip/hip_runtime.h>
#include <hip/hip_bf16.h>
#include <stdint.h>

// fp16 intermediates (same MFMA rate as bf16, 8x lower rounding error --
// safety margin for the triple weight fold W1*Wo*Wv).
typedef _Float16 h16_t;
typedef __attribute__((ext_vector_type(8))) _Float16 h16x8;
typedef __attribute__((ext_vector_type(4))) _Float16 h16x4;
typedef __attribute__((ext_vector_type(4))) float f32x4;

static constexpr int HDIM  = 2048;   // hidden dim
static constexpr int NBATCH = 4;
static constexpr int SEQ   = 2048;
static constexpr int MROWS = NBATCH * SEQ;  // 8192

// ---------------------------------------------------------------------------
// async global->LDS, 16B per lane. LDS dest = wave-uniform base + lane*16.
// ---------------------------------------------------------------------------
__device__ __forceinline__ void gload_lds16(const h16_t* g, h16_t* l) {
  __builtin_amdgcn_global_load_lds(
      (const __attribute__((address_space(1))) void*)g,
      (__attribute__((address_space(3))) void*)l, 16, 0, 0);
}

// ---------------------------------------------------------------------------
// NT GEMM: C[m,n] = sum_k A[m,k]*B[n,k].  A:(M,K) f16 row-major, B:(N,K) f16.
// 128x128 block tile, BK=64, 256 threads = 4 waves in 2x2, each wave 4x4
// mfma_f32_16x16x32_f16 tiles.  M,N,K multiples of 128 (no bounds checks).
//
// LDS tiles XOR-swizzled (R1: killed 2.5e7 conflict cycles/dispatch -> 0).
// Swizzle applied on the GLOBAL address during staging (global_load_lds
// forces lane-order-contiguous LDS writes — m104/m108), inverted on ds_read.
//
// MODE 0: C f16.  MODE 2: atomicAdd(out, sum relu(c)*w2c[n]).
// ---------------------------------------------------------------------------
template<int MODE>
__global__ __launch_bounds__(256)
void gemm_nt(const h16_t* __restrict__ Abase, const h16_t* __restrict__ Bbase,
             void* __restrict__ Cbase, int M, int N, int K,
             long long sAz, long long sBz, long long sCz,
             const float* __restrict__ w2c, float* __restrict__ outp)
{
  __shared__ __align__(16) h16_t sA[128 * 64];
  __shared__ __align__(16) h16_t sB[128 * 64];

  const int tid  = threadIdx.x;
  const int wid  = tid >> 6;        // wave 0..3
  const int lane = tid & 63;
  const int bn = blockIdx.x, bm = blockIdx.y, z = blockIdx.z;

  const h16_t* A = Abase + (long long)z * sAz + (long long)bm * 128 * K;
  const h16_t* B = Bbase + (long long)z * sBz + (long long)bn * 128 * K;

  const int wr  = (wid >> 1) << 6;  // wave row offset (0 or 64)
  const int wc  = (wid & 1) << 6;   // wave col offset (0 or 64)
  const int m16 = lane & 15;
  const int q4  = lane >> 4;        // quad 0..3
  const int sx  = m16 & 7;          // per-lane read-side swizzle xor

  f32x4 acc[4][4];
#pragma unroll
  for (int i = 0; i < 4; i++)
#pragma unroll
    for (int j = 0; j < 4; j++)
#pragma unroll
      for (int r = 0; r < 4; r++) acc[i][j][r] = 0.0f;

  for (int k0 = 0; k0 < K; k0 += 64) {
    __syncthreads();  // previous iteration's LDS reads complete
    // --- stage A,B tiles: 16KB each = 1024 x16B chunks; 4 rounds of 256 ---
    // physical slot cid=(row,p) fetches logical K-octet (p ^ (row&7))
#pragma unroll
    for (int rnd = 0; rnd < 4; rnd++) {
      const int cid  = rnd * 256 + tid;     // chunk id == LDS slot
      const int row  = cid >> 3;            // 8 chunks (128B) per row of 64 f16
      const int koct = (cid & 7) ^ (row & 7);
      const long long goff = (long long)row * K + k0 + koct * 8;
      h16_t* la = sA + (rnd * 256 + wid * 64) * 8;  // wave-uniform LDS base
      h16_t* lb = sB + (rnd * 256 + wid * 64) * 8;
      gload_lds16(A + goff, la);
      gload_lds16(B + goff, lb);
    }
    __syncthreads();  // compiler drains vmcnt before s_barrier

    // --- compute: 2 K-halves x 16 MFMA ---
#pragma unroll
    for (int kk = 0; kk < 64; kk += 32) {
      const int ob = (kk >> 3);             // logical octet base: 0 or 4
      h16x8 fa[4], fb[4];
#pragma unroll
      for (int i = 0; i < 4; i++) {
        const int po = (ob + q4) ^ sx;      // physical octet after swizzle
        fa[i] = *(const h16x8*)(sA + (wr + i * 16 + m16) * 64 + po * 8);
      }
#pragma unroll
      for (int j = 0; j < 4; j++) {
        const int po = (ob + q4) ^ sx;
        fb[j] = *(const h16x8*)(sB + (wc + j * 16 + m16) * 64 + po * 8);
      }
#pragma unroll
      for (int i = 0; i < 4; i++)
#pragma unroll
        for (int j = 0; j < 4; j++)
          acc[i][j] = __builtin_amdgcn_mfma_f32_16x16x32_f16(
              fa[i], fb[j], acc[i][j], 0, 0, 0);
    }
  }

  // C/D layout (m89/m91; dtype-independent m121/m127):
  // col = lane&15, row = (lane>>4)*4 + reg
  const int gr0 = bm * 128 + wr + q4 * 4;
  const int gc0 = bn * 128 + wc + m16;

  if (MODE == 0) {
    h16_t* C = (h16_t*)Cbase + (long long)z * sCz;
#pragma unroll
    for (int i = 0; i < 4; i++)
#pragma unroll
      for (int r = 0; r < 4; r++) {
        const long long ro = (long long)(gr0 + i * 16 + r) * N;
#pragma unroll
        for (int j = 0; j < 4; j++)
          C[ro + gc0 + j * 16] = (h16_t)acc[i][j][r];
      }
  } else {
    float w2[4];
#pragma unroll
    for (int j = 0; j < 4; j++) w2[j] = w2c[gc0 + j * 16];
    float s = 0.f;
#pragma unroll
    for (int i = 0; i < 4; i++)
#pragma unroll
      for (int j = 0; j < 4; j++)
#pragma unroll
        for (int r = 0; r < 4; r++) {
          const float v = acc[i][j][r];
          s += (v > 0.f) ? v * w2[j] : 0.f;
        }
#pragma unroll
    for (int off = 32; off > 0; off >>= 1) s += __shfl_down(s, off, 64);
    __shared__ float red[4];
    if (lane == 0) red[wid] = s;
    __syncthreads();
    if (tid == 0) atomicAdd(outp, red[0] + red[1] + red[2] + red[3]);
  }
}

// ---------------------------------------------------------------------------
// helpers
// ---------------------------------------------------------------------------
__global__ void cvt_h16_kernel(const float* __restrict__ in,
                               h16_t* __restrict__ out, long long n4) {
  const long long i = (long long)blockIdx.x * blockDim.x + threadIdx.x;
  if (i < n4) {
    const float4 v = ((const float4*)in)[i];
    h16x4 o;
    o[0] = (h16_t)v.x; o[1] = (h16_t)v.y; o[2] = (h16_t)v.z; o[3] = (h16_t)v.w;
    ((h16x4*)out)[i] = o;
  }
}

// out[h,m] = in[m,h], fp32 -> f16.  grid(64,64), block(32,8)
__global__ void transpose_cvt_kernel(const float* __restrict__ in,
                                     h16_t* __restrict__ out) {
  __shared__ float t[32][33];
  const int bx = blockIdx.x * 32, by = blockIdx.y * 32;
  const int x = threadIdx.x, y0 = threadIdx.y;
  for (int y = y0; y < 32; y += 8)
    t[y][x] = in[(long long)(by + y) * HDIM + bx + x];
  __syncthreads();
  for (int y = y0; y < 32; y += 8)
    out[(long long)(bx + y) * HDIM + by + x] = (h16_t)t[x][y];
}

__global__ void zero_kernel(float* __restrict__ w2c, float* __restrict__ outp) {
  const int t = blockIdx.x * blockDim.x + threadIdx.x;
  if (t < HDIM) w2c[t] = 0.f;
  if (t == 0) outp[0] = 0.f;
}

// w2c[h] += sum over 128 rows of W2[d,h].  grid(8,16), block 256
__global__ void colsum_kernel(const float* __restrict__ W2,
                              float* __restrict__ w2c) {
  const int h  = blockIdx.x * 256 + threadIdx.x;
  const int d0 = blockIdx.y * 128;
  float s = 0.f;
#pragma unroll 4
  for (int d = 0; d < 128; d++) s += W2[(long long)(d0 + d) * HDIM + h];
  atomicAdd(&w2c[h], s);
}

// in-place row softmax on f16 logits: row of 2048, grid=MROWS, block 256.
__global__ __launch_bounds__(256)
void softmax_h16_kernel(h16_t* __restrict__ S) {
  const long long row = blockIdx.x;
  h16_t* s = S + row * HDIM;
  const int t = threadIdx.x;
  const int wid = t >> 6, lane = t & 63;
  const h16x8 raw = ((const h16x8*)s)[t];
  float v[8];
  float mx = -3.0e38f;
#pragma unroll
  for (int i = 0; i < 8; i++) { v[i] = (float)raw[i]; mx = fmaxf(mx, v[i]); }
#pragma unroll
  for (int off = 32; off > 0; off >>= 1) mx = fmaxf(mx, __shfl_xor(mx, off, 64));
  __shared__ float sred[4];
  if (lane == 0) sred[wid] = mx;
  __syncthreads();
  mx = fmaxf(fmaxf(sred[0], sred[1]), fmaxf(sred[2], sred[3]));
  float sum = 0.f;
#pragma unroll
  for (int i = 0; i < 8; i++) { v[i] = __expf(v[i] - mx); sum += v[i]; }
#pragma unroll
  for (int off = 32; off > 0; off >>= 1) sum += __shfl_xor(sum, off, 64);
  __syncthreads();  // before reusing sred
  if (lane == 0) sred[wid] = sum;
  __syncthreads();
  sum = sred[0] + sred[1] + sred[2] + sred[3];
  const float inv = 1.0f / sum;
  h16x8 o;
#pragma unroll
  for (int i = 0; i < 8; i++) o[i] = (h16_t)(v[i] * inv);
  ((h16x8*)s)[t] = o;
}

// ---------------------------------------------------------------------------
extern "C" void kernel_launch(void* const* d_in, const int* in_sizes, int n_in,
                              void* d_out, int out_size, void* d_ws, size_t ws_size,
                              hipStream_t stream)
{
  const float* x  = (const float*)d_in[0];
  const float* Wq = (const float*)d_in[1];
  const float* Wk = (const float*)d_in[2];
  const float* Wv = (const float*)d_in[3];
  const float* Wo = (const float*)d_in[4];
  const float* W1 = (const float*)d_in[5];
  const float* W2 = (const float*)d_in[6];
  float* out = (float*)d_out;

  const long long HH = (long long)HDIM * HDIM;   // 4,194,304
  const long long XE = (long long)MROWS * HDIM;  // 16,777,216

  // Algebra: only 4 big GEMMs are essential.
  //   score = x (Wq^T Wk) x^T                       -> t-GEMM + score-GEMM
  //   h     = relu(P x (W1 Wo Wv)^T) = relu(P u)    -> uT-GEMM + final-GEMM
  //   out   = sum h . colsum(W2)                    -> MODE-2 epilogue
  // Weight folds (R5 bugfix: GT needs B = plain Wo, NOT WoT):
  //   GT[m,n] = (Wv^T Wo^T)[m,n] = sum_d WvT[m,d]*Wo[n,d]
  //   z=2 batch: {A: WkT,WvT} x {B: WqT,Wob} -> {C: WqkT,GT}
  //   then Wvow = W1 . G (dependent fold).
  char* p = (char*)d_ws;
  h16_t* xb   = (h16_t*)p; p += XE * 2;  // x f16
  h16_t* WkT  = (h16_t*)p; p += HH * 2;  // fold A-batch, z=0
  h16_t* WvT  = (h16_t*)p; p += HH * 2;  // fold A-batch, z=1
  h16_t* WqT  = (h16_t*)p; p += HH * 2;  // fold B-batch, z=0
  h16_t* Wob  = (h16_t*)p; p += HH * 2;  // fold B-batch, z=1 (PLAIN Wo)
  h16_t* WqkT = (h16_t*)p; p += HH * 2;  // fold C-batch, z=0
  h16_t* GT   = (h16_t*)p; p += HH * 2;  // fold C-batch, z=1
  h16_t* W1b  = (h16_t*)p; p += HH * 2;
  h16_t* Wvow = (h16_t*)p; p += HH * 2;
  h16_t* tb   = (h16_t*)p; p += XE * 2;  // t, then uT (t dead after score)
  h16_t* sc   = (h16_t*)p; p += XE * 2;  // score -> P (in-place softmax)
  float* w2c  = (float*)p;  p += HDIM * 4;

  const dim3 b256(256);

  // 0. zero accumulators (d_out / d_ws re-poisoned 0xAA before every launch)
  zero_kernel<<<dim3(8), b256, 0, stream>>>(w2c, out);

  // 1. converts: x, Wo, W1 plain; Wk, Wv, Wq transposed; W2 column sums
  cvt_h16_kernel<<<dim3((unsigned)(XE / 4 / 256)), b256, 0, stream>>>(x, xb, XE / 4);
  transpose_cvt_kernel<<<dim3(64, 64), dim3(32, 8), 0, stream>>>(Wk, WkT);
  transpose_cvt_kernel<<<dim3(64, 64), dim3(32, 8), 0, stream>>>(Wv, WvT);
  transpose_cvt_kernel<<<dim3(64, 64), dim3(32, 8), 0, stream>>>(Wq, WqT);
  cvt_h16_kernel<<<dim3((unsigned)(HH / 4 / 256)), b256, 0, stream>>>(Wo, Wob, HH / 4);
  cvt_h16_kernel<<<dim3((unsigned)(HH / 4 / 256)), b256, 0, stream>>>(W1, W1b, HH / 4);
  colsum_kernel<<<dim3(8, 16), b256, 0, stream>>>(W2, w2c);

  // 2a. batched fold z=2:
  //   z=0: WqkT[m,n] = sum_d Wk[d,m]*Wq[d,n]  ( = (Wq^T Wk)^T )
  //   z=1: GT[m,n]   = sum_d Wv[d,m]*Wo[n,d]  ( = (Wo Wv)^T )
  gemm_nt<0><<<dim3(16, 16, 2), b256, 0, stream>>>(WkT, WqT, WqkT,
      HDIM, HDIM, HDIM, HH, HH, HH, nullptr, nullptr);
  // 2b. Wvow[m,n] = sum_k W1[m,k]*GT[n,k] = (W1 Wo Wv)[m,n]
  gemm_nt<0><<<dim3(16, 16, 1), b256, 0, stream>>>(W1b, GT, Wvow,
      HDIM, HDIM, HDIM, 0, 0, 0, nullptr, nullptr);

  // 3. t = x @ Wqk   (t[m,n] = sum_k x[m,k]*WqkT[n,k])
  gemm_nt<0><<<dim3(16, 64, 1), b256, 0, stream>>>(xb, WqkT, tb,
      MROWS, HDIM, HDIM, 0, 0, 0, nullptr, nullptr);

  // 4. score[b,i,j] = sum_e t[b,i,e]*x[b,j,e]  (f16 logits)
  gemm_nt<0><<<dim3(16, 16, 4), b256, 0, stream>>>(tb, xb, sc,
      HDIM, HDIM, HDIM, HH, HH, HH, nullptr, nullptr);

  // 5. P = softmax(score), in place
  softmax_h16_kernel<<<dim3(MROWS), b256, 0, stream>>>(sc);

  // 6. uT[b,e,j] = sum_h Wvow[e,h]*x[b,j,h]   (t dead -> reuse tb)
  gemm_nt<0><<<dim3(16, 16, 4), b256, 0, stream>>>(Wvow, xb, tb,
      HDIM, HDIM, HDIM, 0, HH, HH, nullptr, nullptr);

  // 7. out += sum relu( P @ u ) . w2c   (z[b,i,e] = sum_j P[b,i,j]*uT[b,e,j])
  gemm_nt<2><<<dim3(16, 16, 4), b256, 0, stream>>>(sc, tb, nullptr,
      HDIM, HDIM, HDIM, HH, HH, 0, w2c, out);
}

// Round 7
// 626.316 us; speedup vs baseline: 1.3377x; 1.0688x over previous
//
#include <hip/hip_runtime.h>
#include <hip/hip_bf16.h>
#include <stdint.h>

typedef _Float16 h16_t;
typedef __attribute__((ext_vector_type(8))) _Float16 h16x8;
typedef __attribute__((ext_vector_type(4))) _Float16 h16x4;
typedef __attribute__((ext_vector_type(16))) float f32x16;

static constexpr int HDIM  = 2048;
static constexpr int MROWS = 8192;                   // 4 batches x 2048

// ---------------------------------------------------------------------------
__device__ __forceinline__ void gload_lds16(const h16_t* g, h16_t* l) {
  __builtin_amdgcn_global_load_lds(
      (const __attribute__((address_space(1))) void*)g,
      (__attribute__((address_space(3))) void*)l, 16, 0, 0);
}

// ---------------------------------------------------------------------------
// NT GEMM core: C[m,n] = sum_k A[m,k]*B[n,k], K = N = 2048 hardcoded.
// 128x128 block tile, BK=64, 4 waves 2x2, wave tile 64x64 = 2x2 tiles of
// mfma_f32_32x32x16_f16 (R6: 32x32 retires 2x FLOP/inst at ~8 vs ~4.85 cyc
// -> -17% MFMA-pipe time, same ds_read/VALU).  XOR-swizzled LDS (R1: 0
// bank conflicts), swizzle applied on the global address during staging
// (global_load_lds is lane-order-contiguous, m104/m108).
// A points at the bm-tile row block (A + bm*128*2048), B at bn-tile block.
// ---------------------------------------------------------------------------
__device__ __forceinline__ void gemm_core(const h16_t* __restrict__ A,
                                          const h16_t* __restrict__ B,
                                          f32x16 acc[2][2],
                                          h16_t* sA, h16_t* sB) {
  const int tid  = threadIdx.x;
  const int wid  = tid >> 6;
  const int lane = tid & 63;
  const int wr  = (wid >> 1) << 6;
  const int wc  = (wid & 1) << 6;
  const int l31 = lane & 31;
  const int hi  = lane >> 5;
  const int sx  = lane & 7;

#pragma unroll
  for (int i = 0; i < 2; i++)
#pragma unroll
    for (int j = 0; j < 2; j++)
#pragma unroll
      for (int r = 0; r < 16; r++) acc[i][j][r] = 0.0f;

  for (int k0 = 0; k0 < 2048; k0 += 64) {
    __syncthreads();
#pragma unroll
    for (int rnd = 0; rnd < 4; rnd++) {
      const int cid  = rnd * 256 + tid;
      const int row  = cid >> 3;
      const int koct = (cid & 7) ^ (row & 7);
      const long long goff = (long long)row * 2048 + k0 + koct * 8;
      gload_lds16(A + goff, sA + (rnd * 256 + wid * 64) * 8);
      gload_lds16(B + goff, sB + (rnd * 256 + wid * 64) * 8);
    }
    __syncthreads();

#pragma unroll
    for (int ko = 0; ko < 4; ko++) {
      const int po = (2 * ko + hi) ^ sx;   // logical octet 2ko+hi, de-swizzled
      h16x8 fa[2], fb[2];
#pragma unroll
      for (int i = 0; i < 2; i++)
        fa[i] = *(const h16x8*)(sA + (wr + i * 32 + l31) * 64 + po * 8);
#pragma unroll
      for (int j = 0; j < 2; j++)
        fb[j] = *(const h16x8*)(sB + (wc + j * 32 + l31) * 64 + po * 8);
#pragma unroll
      for (int i = 0; i < 2; i++)
#pragma unroll
        for (int j = 0; j < 2; j++)
          acc[i][j] = __builtin_amdgcn_mfma_f32_32x32x16_f16(
              fa[i], fb[j], acc[i][j], 0, 0, 0);
    }
  }
}

// C/D layout 32x32 (m74/m101 HW-verified): col=lane&31,
// row=(reg&3)+8*(reg>>2)+4*(lane>>5), reg in [0,16)
__device__ __forceinline__ void store_c(h16_t* __restrict__ C,
                                        f32x16 acc[2][2], int bm, int bn) {
  const int tid  = threadIdx.x;
  const int wid  = tid >> 6;
  const int lane = tid & 63;
  const int wr = (wid >> 1) << 6, wc = (wid & 1) << 6;
  const int l31 = lane & 31, hi = lane >> 5;
  const int gr = bm * 128 + wr + 4 * hi;
  const int gc = bn * 128 + wc + l31;
#pragma unroll
  for (int i = 0; i < 2; i++)
#pragma unroll
    for (int r = 0; r < 16; r++) {
      const int row = gr + i * 32 + (r & 3) + 8 * (r >> 2);
      const long long ro = (long long)row * 2048;
#pragma unroll
      for (int j = 0; j < 2; j++)
        C[ro + gc + j * 32] = (h16_t)acc[i][j][r];
    }
}

// ---------------------------------------------------------------------------
// batched MODE-0 GEMM (fold2a z=2; score z=4)
__global__ __launch_bounds__(256)
void gemm_b(const h16_t* __restrict__ Ab, const h16_t* __restrict__ Bb,
            h16_t* __restrict__ Cb, long long sAz, long long sBz, long long sCz)
{
  __shared__ __align__(16) h16_t sA[128 * 64];
  __shared__ __align__(16) h16_t sB[128 * 64];
  const int bn = blockIdx.x, bm = blockIdx.y, z = blockIdx.z;
  const h16_t* A = Ab + (long long)z * sAz + (long long)bm * 128 * 2048;
  const h16_t* B = Bb + (long long)z * sBz + (long long)bn * 128 * 2048;
  f32x16 acc[2][2];
  gemm_core(A, B, acc, sA, sB);
  store_c(Cb + (long long)z * sCz, acc, bm, bn);
}

// t-GEMM (z=0, M=8192) with the dependent weight fold Wvow=W1.G riding z=1
// (256 fold blocks hide inside the 1024-block t-GEMM launch).
__global__ __launch_bounds__(256)
void gemm_t_fold(const h16_t* __restrict__ xb, const h16_t* __restrict__ WqkT,
                 h16_t* __restrict__ tb,
                 const h16_t* __restrict__ W1b, const h16_t* __restrict__ GT,
                 h16_t* __restrict__ Wvow)
{
  const int bn = blockIdx.x, bm = blockIdx.y, z = blockIdx.z;
  if (z == 1 && bm >= 16) return;
  __shared__ __align__(16) h16_t sA[128 * 64];
  __shared__ __align__(16) h16_t sB[128 * 64];
  const h16_t* A; const h16_t* B; h16_t* C;
  if (z == 0) { A = xb;  B = WqkT; C = tb; }
  else        { A = W1b; B = GT;   C = Wvow; }
  A += (long long)bm * 128 * 2048;
  B += (long long)bn * 128 * 2048;
  f32x16 acc[2][2];
  gemm_core(A, B, acc, sA, sB);
  store_c(C, acc, bm, bn);
}

// uT GEMM (z<4: uT[b,e,j] = sum_h Wvow[e,h]*x[b,j,h]) with the in-place
// softmax of sc riding z>=4 (8192 row-blocks).
__global__ __launch_bounds__(256)
void gemm_ut_softmax(const h16_t* __restrict__ Wvow, const h16_t* __restrict__ xb,
                     h16_t* __restrict__ ut, h16_t* __restrict__ sc)
{
  const int bn = blockIdx.x, bm = blockIdx.y, z = blockIdx.z;
  const int t = threadIdx.x;
  if (z >= 4) {
    // softmax on row (z-4)*256 + bm*16 + bn of sc (2048 f16, in place)
    const long long row = (long long)(z - 4) * 256 + bm * 16 + bn;
    h16_t* s = sc + row * 2048;
    const int wid = t >> 6, lane = t & 63;
    const h16x8 raw = ((const h16x8*)s)[t];
    float v[8];
    float mx = -3.0e38f;
#pragma unroll
    for (int i = 0; i < 8; i++) { v[i] = (float)raw[i]; mx = fmaxf(mx, v[i]); }
#pragma unroll
    for (int off = 32; off > 0; off >>= 1) mx = fmaxf(mx, __shfl_xor(mx, off, 64));
    __shared__ float sred[4];
    if (lane == 0) sred[wid] = mx;
    __syncthreads();
    mx = fmaxf(fmaxf(sred[0], sred[1]), fmaxf(sred[2], sred[3]));
    float sum = 0.f;
#pragma unroll
    for (int i = 0; i < 8; i++) { v[i] = __expf(v[i] - mx); sum += v[i]; }
#pragma unroll
    for (int off = 32; off > 0; off >>= 1) sum += __shfl_xor(sum, off, 64);
    __syncthreads();
    if (lane == 0) sred[wid] = sum;
    __syncthreads();
    sum = sred[0] + sred[1] + sred[2] + sred[3];
    const float inv = 1.0f / sum;
    h16x8 o;
#pragma unroll
    for (int i = 0; i < 8; i++) o[i] = (h16_t)(v[i] * inv);
    ((h16x8*)s)[t] = o;
    return;
  }
  __shared__ __align__(16) h16_t sA[128 * 64];
  __shared__ __align__(16) h16_t sB[128 * 64];
  const h16_t* A = Wvow + (long long)bm * 128 * 2048;
  const h16_t* B = xb + (long long)z * (long long)MROWS / 4 * 2048 * 2
                      /*...*/;
  // NOTE: stride is HH elements per batch: rewrite cleanly below
  B = xb + (long long)z * 2048 * 2048 + (long long)bn * 128 * 2048;
  f32x16 acc[2][2];
  gemm_core(A, B, acc, sA, sB);
  store_c(ut + (long long)z * 2048 * 2048, acc, bm, bn);
}

// final: out += sum relu(P @ u) . colsum(W2); w2 from 16 partials
__global__ __launch_bounds__(256)
void gemm_final(const h16_t* __restrict__ P, const h16_t* __restrict__ ut,
                const float* __restrict__ w2p, float* __restrict__ outp)
{
  __shared__ __align__(16) h16_t sA[128 * 64];
  __shared__ __align__(16) h16_t sB[128 * 64];
  const int bn = blockIdx.x, bm = blockIdx.y, z = blockIdx.z;
  const h16_t* A = P  + (long long)z * 2048 * 2048 + (long long)bm * 128 * 2048;
  const h16_t* B = ut + (long long)z * 2048 * 2048 + (long long)bn * 128 * 2048;
  f32x16 acc[2][2];
  gemm_core(A, B, acc, sA, sB);

  const int tid  = threadIdx.x;
  const int wid  = tid >> 6;
  const int lane = tid & 63;
  const int wc = (wid & 1) << 6, l31 = lane & 31;
  const int gc = bn * 128 + wc + l31;
  float w2j[2];
#pragma unroll
  for (int j = 0; j < 2; j++) {
    const int col = gc + j * 32;
    float s = 0.f;
#pragma unroll
    for (int c = 0; c < 16; c++) s += w2p[c * 2048 + col];
    w2j[j] = s;
  }
  float s = 0.f;
#pragma unroll
  for (int i = 0; i < 2; i++)
#pragma unroll
    for (int j = 0; j < 2; j++)
#pragma unroll
      for (int r = 0; r < 16; r++) {
        const float v = acc[i][j][r];
        s += (v > 0.f) ? v * w2j[j] : 0.f;
      }
#pragma unroll
  for (int off = 32; off > 0; off >>= 1) s += __shfl_down(s, off, 64);
  __shared__ float red[4];
  if (lane == 0) red[wid] = s;
  __syncthreads();
  if (tid == 0) atomicAdd(outp, red[0] + red[1] + red[2] + red[3]);
}

// ---------------------------------------------------------------------------
// mega-prologue: one launch for all converts / transposes / colsum / zero.
// segments by blockIdx.x; every block takes exactly one branch.
__global__ __launch_bounds__(256)
void prologue_kernel(const float* __restrict__ x,  const float* __restrict__ Wq,
                     const float* __restrict__ Wk, const float* __restrict__ Wv,
                     const float* __restrict__ Wo, const float* __restrict__ W1,
                     const float* __restrict__ W2,
                     h16_t* __restrict__ xb,  h16_t* __restrict__ WkT,
                     h16_t* __restrict__ WvT, h16_t* __restrict__ WqT,
                     h16_t* __restrict__ Wob, h16_t* __restrict__ W1b,
                     float* __restrict__ w2p, float* __restrict__ outp)
{
  const int t = threadIdx.x;
  int b = blockIdx.x;
  if (b < 16384) {                       // x: fp32 -> f16, 4/thread
    const long long i = (long long)b * 256 + t;
    const float4 v = ((const float4*)x)[i];
    h16x4 o;
    o[0] = (h16_t)v.x; o[1] = (h16_t)v.y; o[2] = (h16_t)v.z; o[3] = (h16_t)v.w;
    ((h16x4*)xb)[i] = o;
    return;
  }
  b -= 16384;
  if (b < 12288) {                       // Wk,Wv,Wq transposed converts
    const float* src; h16_t* dst;
    if (b < 4096)      { src = Wk; dst = WkT; }
    else if (b < 8192) { src = Wv; dst = WvT; b -= 4096; }
    else               { src = Wq; dst = WqT; b -= 8192; }
    __shared__ float tl[32][33];
    const int bx = (b & 63) * 32, by = (b >> 6) * 32;
    const int xx = t & 31, y0 = t >> 5;
    for (int y = y0; y < 32; y += 8)
      tl[y][xx] = src[(long long)(by + y) * 2048 + bx + xx];
    __syncthreads();
    for (int y = y0; y < 32; y += 8)
      dst[(long long)(bx + y) * 2048 + by + xx] = (h16_t)tl[xx][y];
    return;
  }
  b -= 12288;
  if (b < 8192) {                        // Wo, W1 plain converts
    const float* src = (b < 4096) ? Wo : W1;
    h16_t* dst = (b < 4096) ? Wob : W1b;
    const long long i = (long long)(b & 4095) * 256 + t;
    const float4 v = ((const float4*)src)[i];
    h16x4 o;
    o[0] = (h16_t)v.x; o[1] = (h16_t)v.y; o[2] = (h16_t)v.z; o[3] = (h16_t)v.w;
    ((h16x4*)dst)[i] = o;
    return;
  }
  b -= 8192;
  if (b < 128) {                         // W2 colsum partials (non-atomic)
    const int c = b >> 3;
    const int h = (b & 7) * 256 + t;
    float s = 0.f;
#pragma unroll 4
    for (int d = 0; d < 128; d++) s += W2[(long long)(c * 128 + d) * 2048 + h];
    w2p[c * 2048 + h] = s;
    return;
  }
  b -= 128;
  if (b == 0 && t == 0) outp[0] = 0.f;   // zero the output accumulator
}

// ---------------------------------------------------------------------------
extern "C" void kernel_launch(void* const* d_in, const int* in_sizes, int n_in,
                              void* d_out, int out_size, void* d_ws, size_t ws_size,
                              hipStream_t stream)
{
  const float* x  = (const float*)d_in[0];
  const float* Wq = (const float*)d_in[1];
  const float* Wk = (const float*)d_in[2];
  const float* Wv = (const float*)d_in[3];
  const float* Wo = (const float*)d_in[4];
  const float* W1 = (const float*)d_in[5];
  const float* W2 = (const float*)d_in[6];
  float* out = (float*)d_out;

  const long long HH = (long long)HDIM * HDIM;   // 4,194,304
  const long long XE = (long long)MROWS * HDIM;  // 16,777,216

  // Algebra (R3..R5): 4 essential big GEMMs.
  //   score = x (Wq^T Wk) x^T;  h = relu(P x (W1 Wo Wv)^T);  out = sum h.colsum(W2)
  // Folds: batched z=2 {WkT,WvT}x{WqT,Wob} -> {WqkT, GT=(Wo Wv)^T};
  //        then Wvow = W1.G rides z=1 of the t-GEMM launch.
  char* p = (char*)d_ws;
  h16_t* xb   = (h16_t*)p; p += XE * 2;
  h16_t* WkT  = (h16_t*)p; p += HH * 2;  // fold A, z=0
  h16_t* WvT  = (h16_t*)p; p += HH * 2;  // fold A, z=1
  h16_t* WqT  = (h16_t*)p; p += HH * 2;  // fold B, z=0
  h16_t* Wob  = (h16_t*)p; p += HH * 2;  // fold B, z=1 (plain Wo)
  h16_t* WqkT = (h16_t*)p; p += HH * 2;  // fold C, z=0
  h16_t* GT   = (h16_t*)p; p += HH * 2;  // fold C, z=1
  h16_t* W1b  = (h16_t*)p; p += HH * 2;
  h16_t* Wvow = (h16_t*)p; p += HH * 2;
  h16_t* tb   = (h16_t*)p; p += XE * 2;  // t, then uT
  h16_t* sc   = (h16_t*)p; p += XE * 2;  // score -> P in place
  float* w2p  = (float*)p; p += 16 * HDIM * 4;

  const dim3 b256(256);

  // 1. mega-prologue (one launch): converts, transposes, colsum, zero-out
  prologue_kernel<<<dim3(16384 + 12288 + 8192 + 128 + 1), b256, 0, stream>>>(
      x, Wq, Wk, Wv, Wo, W1, W2, xb, WkT, WvT, WqT, Wob, W1b, w2p, out);

  // 2. batched fold z=2: WqkT = (Wq^T Wk)^T ; GT = (Wo Wv)^T
  gemm_b<<<dim3(16, 16, 2), b256, 0, stream>>>(WkT, WqT, WqkT, HH, HH, HH);

  // 3. t = x@Wqk (z=0, M=8192)  +  Wvow = W1.G fold (z=1)
  gemm_t_fold<<<dim3(16, 64, 2), b256, 0, stream>>>(xb, WqkT, tb, W1b, GT, Wvow);

  // 4. score[b,i,j] = sum_e t[b,i,e]*x[b,j,e]
  gemm_b<<<dim3(16, 16, 4), b256, 0, stream>>>(tb, xb, sc, HH, HH, HH);

  // 5. uT[b,e,j] = sum_h Wvow[e,h]*x[b,j,h] (z<4, into tb)  +  softmax(sc) (z>=4)
  gemm_ut_softmax<<<dim3(16, 16, 36), b256, 0, stream>>>(Wvow, xb, tb, sc);

  // 6. out += sum relu(P @ u) . w2
  gemm_final<<<dim3(16, 16, 4), b256, 0, stream>>>(sc, tb, w2p, out);
}